// Round 1
// baseline (490.343 us; speedup 1.0000x reference)
//
#include <hip/hip_runtime.h>

#define ROWSB 32
#define HIDN 256
#define TT 8
#define EPSI 1e-6f

#define VSTR 36    // vocV stride (floats)
#define HSTR 36    // haT stride: haT[j][row], row-dim padded to 36
#define TBSTR 40   // tokbuf stride
#define HSB 260    // hs staging stride (aliases haT region)
#define CBS 260    // comm buffer stride (aliases vocV region)

__device__ __forceinline__ void ld4(float* d, const float* p) {
  float4 v = *(const float4*)p;
  d[0] = v.x; d[1] = v.y; d[2] = v.z; d[3] = v.w;
}

__global__ __launch_bounds__(256, 2)
void mac_fused(const float* __restrict__ hs, const float* __restrict__ eps,
               const float* __restrict__ WQ, const float* __restrict__ bQ,
               const float* __restrict__ WK, const float* __restrict__ bK,
               const float* __restrict__ Wmu, const float* __restrict__ bmu,
               const float* __restrict__ Wvar, const float* __restrict__ bvar,
               const float* __restrict__ vocab,
               const float* __restrict__ Wsum, const float* __restrict__ bsum,
               const float* __restrict__ Whead, const float* __restrict__ bhead,
               float* __restrict__ out, int Btot)
{
  // 79 KB total -> 2 blocks/CU
  __shared__ __align__(16) float vocV[257*VSTR + 28];   // [vocab v][dim]; tail aliased by comm/o1 buffers
  __shared__ __align__(16) float haT[HIDN*HSTR];        // [j][row] swizzled; aliases hs-stage + GEMV partials
  __shared__ __align__(16) float tokbuf[ROWSB*TBSTR];   // [row][dim]
  __shared__ float finbuf[ROWSB];

  const int t   = threadIdx.x;
  const int c4  = t & 63;        // column-quad id: flat cols 4*c4..4*c4+3
  const int rg  = t >> 6;        // row group: rows 8*rg..8*rg+7 (one agent group)
  const int sr  = t >> 3;        // sampling layout: row
  const int sc8 = t & 7;         // sampling layout: dim chunk (4 dims)
  const int d0u = (c4 << 2) & 31;// this thread's comp-dims (unified layout)
  const int tg  = c4 >> 3;       // token slot this thread's cols belong to
  const int rowbase = blockIdx.x * ROWSB;

  float Qr[8][4], Vr[8][4], Kr[8][4], MSGr[8][4];
  float eosv[4];
  unsigned fin = 0u;

  // ---------------- phase 0: stage hs + vocab, init ----------------
  {
    const float* hp = hs + (size_t)(rowbase + rg*8)*HIDN + c4*4;
    #pragma unroll
    for (int rr = 0; rr < 8; ++rr)
      *(float4*)&haT[(rg*8+rr)*HSB + c4*4] = *(const float4*)(hp + (size_t)rr*HIDN);
  }
  for (int v = t; v < 257; v += 256) {
    #pragma unroll
    for (int m = 0; m < 8; ++m)
      *(float4*)&vocV[v*VSTR + m*4] = *(const float4*)(vocab + v*32 + m*4);
  }
  ld4(eosv, vocab + 256*32 + d0u);
  if (t < ROWSB) finbuf[t] = 0.f;
  {
    float bq[4], bk[4];
    ld4(bq, bQ + c4*4); ld4(bk, bK + c4*4);
    #pragma unroll
    for (int rr = 0; rr < 8; ++rr) {
      #pragma unroll
      for (int k = 0; k < 4; ++k) { Qr[rr][k] = bq[k]; Vr[rr][k] = bk[k]; }
    }
  }
  __syncthreads();

  // ------------- initial GEMM: Q = hs@WQ + bQ ; V = hs@WK + bK -------------
  #pragma unroll 2
  for (int jq = 0; jq < 64; ++jq) {
    float hsq[8][4];
    #pragma unroll
    for (int rr = 0; rr < 8; ++rr) ld4(hsq[rr], &haT[(rg*8+rr)*HSB + jq*4]);
    #pragma unroll
    for (int m = 0; m < 4; ++m) {
      float wq[4], wk[4];
      ld4(wq, WQ + (size_t)(jq*4+m)*HIDN + c4*4);
      ld4(wk, WK + (size_t)(jq*4+m)*HIDN + c4*4);
      #pragma unroll
      for (int rr = 0; rr < 8; ++rr) {
        #pragma unroll
        for (int k = 0; k < 4; ++k) {
          Qr[rr][k] += hsq[rr][m]*wq[k];
          Vr[rr][k] += hsq[rr][m]*wk[k];
        }
      }
    }
  }
  {
    float bk[4]; ld4(bk, bK + c4*4);
    #pragma unroll
    for (int rr = 0; rr < 8; ++rr) {
      #pragma unroll
      for (int k = 0; k < 4; ++k) {
        Qr[rr][k] *= (1.0f/256.0f);   // bake NF^2 so logit = -(Qr*Kr), Kr unscaled
        Kr[rr][k]   = bk[k];           // K_acc = m@WK + bK, m starts at 0
        MSGr[rr][k] = 0.f;
      }
    }
  }

  // ---------------- token recurrence ----------------
  for (int it = 0; it < TT; ++it) {
    // --- incremental K update: K += token_{it-1} @ WK[32(it-1) .. 32it) ---
    if (it > 0) {
      const float* Wr = WK + (size_t)((it-1)*32)*HIDN + c4*4;
      #pragma unroll 2
      for (int cq = 0; cq < 8; ++cq) {
        float tq[8][4];
        #pragma unroll
        for (int rr = 0; rr < 8; ++rr) ld4(tq[rr], &tokbuf[(rg*8+rr)*TBSTR + cq*4]);
        #pragma unroll
        for (int m = 0; m < 4; ++m) {
          float w[4]; ld4(w, Wr + (size_t)(cq*4+m)*HIDN);
          #pragma unroll
          for (int rr = 0; rr < 8; ++rr) {
            #pragma unroll
            for (int k = 0; k < 4; ++k) Kr[rr][k] += tq[rr][m]*w[k];
          }
        }
      }
    }

    // --- softmax(-(Q*K)) ; ha = attn*V -> haT (XOR-swizzled rows) ---
    {
      const int sw = ((c4 >> 1) & 7) << 2;   // = ((j>>3)&7)<<2 for j = 4*c4+k
      #pragma unroll
      for (int rr = 0; rr < 8; ++rr) {
        float l[4];
        #pragma unroll
        for (int k = 0; k < 4; ++k) l[k] = -(Qr[rr][k]*Kr[rr][k]);
        float mx = fmaxf(fmaxf(l[0],l[1]), fmaxf(l[2],l[3]));
        #pragma unroll
        for (int off = 32; off >= 1; off >>= 1) mx = fmaxf(mx, __shfl_xor(mx, off));
        float e[4], s = 0.f;
        #pragma unroll
        for (int k = 0; k < 4; ++k) { e[k] = __expf(l[k]-mx); s += e[k]; }
        #pragma unroll
        for (int off = 32; off >= 1; off >>= 1) s += __shfl_xor(s, off);
        float iv = 1.0f / s;
        int pr = (rg*8+rr) ^ sw;
        #pragma unroll
        for (int k = 0; k < 4; ++k)
          haT[(c4*4+k)*HSTR + pr] = e[k]*Vr[rr][k]*iv;
      }
    }
    __syncthreads();

    // --- GEMV: [32 rows x 256] @ [256 x (32 mu | 32 var)], j-split partials ---
    {
      float acc[32];
      #pragma unroll
      for (int r = 0; r < 32; ++r) acc[r] = 0.f;
      const float* Wcol = (c4 < 32) ? (Wmu + c4) : (Wvar + (c4 - 32));
      #pragma unroll 2
      for (int jj = 0; jj < 64; ++jj) {
        int j = rg*64 + jj;
        float w = Wcol[(size_t)j*32];
        int s = (j >> 3) & 7;
        #pragma unroll
        for (int cl = 0; cl < 8; ++cl) {
          float h[4]; ld4(h, &haT[j*HSTR + ((cl ^ s) << 2)]);  // de-swizzle: rows cl*4..cl*4+3
          #pragma unroll
          for (int k = 0; k < 4; ++k) acc[cl*4+k] += h[k]*w;
        }
      }
      __syncthreads();               // all haT reads done before aliasing as partials
      #pragma unroll
      for (int r = 0; r < 32; ++r) haT[rg*2048 + r*64 + c4] = acc[r];
    }
    __syncthreads();

    // --- sample + quantize (layout: row sr, dims 4*sc8..+3) ---
    {
      float mu[4] = {0,0,0,0}, lv[4] = {0,0,0,0};
      #pragma unroll
      for (int g = 0; g < 4; ++g) {
        float pm[4], pv[4];
        ld4(pm, &haT[g*2048 + sr*64 + sc8*4]);
        ld4(pv, &haT[g*2048 + sr*64 + 32 + sc8*4]);
        #pragma unroll
        for (int k = 0; k < 4; ++k) { mu[k] += pm[k]; lv[k] += pv[k]; }
      }
      {
        float bm[4], bv[4];
        ld4(bm, bmu + sc8*4); ld4(bv, bvar + sc8*4);
        #pragma unroll
        for (int k = 0; k < 4; ++k) { mu[k] += bm[k]; lv[k] += bv[k]; }
      }
      float ep[4];
      ld4(ep, eps + ((size_t)it*Btot + rowbase + sr)*32 + sc8*4);
      float tk[4], md[4];
      #pragma unroll
      for (int k = 0; k < 4; ++k) {
        tk[k] = ep[k]*__expf(0.5f*lv[k]) + mu[k];
        md[k] = 3.0e38f;
      }
      #pragma unroll 4
      for (int v = 0; v < 257; ++v) {
        float vv[4]; ld4(vv, &vocV[v*VSTR + sc8*4]);
        #pragma unroll
        for (int k = 0; k < 4; ++k) md[k] = fminf(md[k], fabsf(tk[k]-vv[k]));
      }
      float msk = 1.0f - finbuf[sr];
      *(float4*)&tokbuf[sr*TBSTR + sc8*4] =
          make_float4(md[0]*md[0]*msk, md[1]*md[1]*msk, md[2]*md[2]*msk, md[3]*md[3]*msk);
    }
    __syncthreads();

    // --- hit detection + message update (unified layout) ---
    {
      float tokr[8][4];
      #pragma unroll
      for (int rr = 0; rr < 8; ++rr) ld4(tokr[rr], &tokbuf[(rg*8+rr)*TBSTR + d0u]);
      unsigned newfin = fin;
      #pragma unroll
      for (int rr = 0; rr < 8; ++rr) {
        float pd = 0.f, ed = 0.f;
        #pragma unroll
        for (int k = 0; k < 4; ++k) { float dm = tokr[rr][k]-MSGr[rr][k]; pd += dm*dm; }
        if (tg == 0) {
          #pragma unroll
          for (int k = 0; k < 4; ++k) { float de = tokr[rr][k]-eosv[k]; ed += de*de; }
        }
        // stage A: sum within 8-lane token groups
        pd += __shfl_xor(pd, 1); ed += __shfl_xor(ed, 1);
        pd += __shfl_xor(pd, 2); ed += __shfl_xor(ed, 2);
        pd += __shfl_xor(pd, 4); ed += __shfl_xor(ed, 4);
        float fl = (pd < EPSI && tg < it) ? 1.f : 0.f;
        // stage B: combine across groups (OR via sum; ed only group 0 nonzero)
        fl += __shfl_xor(fl, 8);  ed += __shfl_xor(ed, 8);
        fl += __shfl_xor(fl, 16); ed += __shfl_xor(ed, 16);
        fl += __shfl_xor(fl, 32); ed += __shfl_xor(ed, 32);
        bool hit = (ed < EPSI) || (fl > 0.f);
        if (hit) {
          if ((tg == it) && !((fin >> rr) & 1u)) {   // new_eos -> write EOS token
            #pragma unroll
            for (int k = 0; k < 4; ++k) tokr[rr][k] = eosv[k];
          }
          newfin |= (1u << rr);
        }
        if (tg == it) {
          #pragma unroll
          for (int k = 0; k < 4; ++k) MSGr[rr][k] = tokr[rr][k];
        }
      }
      __syncthreads();   // all tokbuf reads done before rewrite
      if (tg == it) {
        #pragma unroll
        for (int rr = 0; rr < 8; ++rr)
          *(float4*)&tokbuf[(rg*8+rr)*TBSTR + d0u] =
              make_float4(MSGr[rr][0], MSGr[rr][1], MSGr[rr][2], MSGr[rr][3]);
      }
      if (c4 == 0) {
        #pragma unroll
        for (int rr = 0; rr < 8; ++rr)
          finbuf[rg*8+rr] = ((newfin >> rr) & 1u) ? 1.f : 0.f;
      }
      fin = newfin;
    }
    __syncthreads();
  }

  // ---------------- final: comm sum + two GEMVs + relu ----------------
  float* commb = vocV;            // [4][CBS]
  float* o1    = vocV + 4*CBS;    // [4][CBS]
  {
    float cs[4] = {0,0,0,0};
    #pragma unroll
    for (int rr = 0; rr < 8; ++rr) {
      #pragma unroll
      for (int k = 0; k < 4; ++k) cs[k] += MSGr[rr][k];
    }
    const float i7 = 1.0f/7.0f;
    *(float4*)&commb[rg*CBS + c4*4] = make_float4(cs[0]*i7, cs[1]*i7, cs[2]*i7, cs[3]*i7);
  }
  __syncthreads();
  {
    float a1[4] = {0,0,0,0};
    #pragma unroll 2
    for (int jq = 0; jq < 64; ++jq) {
      float w[4];
      #pragma unroll
      for (int m = 0; m < 4; ++m) w[m] = Wsum[(size_t)(jq*4+m)*HIDN + t];
      #pragma unroll
      for (int g = 0; g < 4; ++g) {
        float c[4]; ld4(c, &commb[g*CBS + jq*4]);
        a1[g] += c[0]*w[0] + c[1]*w[1] + c[2]*w[2] + c[3]*w[3];
      }
    }
    float bs = bsum[t];
    #pragma unroll
    for (int g = 0; g < 4; ++g) o1[g*CBS + t] = a1[g] + bs;
  }
  __syncthreads();
  {
    float a2[4] = {0,0,0,0};
    #pragma unroll 2
    for (int jq = 0; jq < 64; ++jq) {
      float w[4];
      #pragma unroll
      for (int m = 0; m < 4; ++m) w[m] = Whead[(size_t)(jq*4+m)*HIDN + t];
      #pragma unroll
      for (int g = 0; g < 4; ++g) {
        float c[4]; ld4(c, &o1[g*CBS + jq*4]);
        a2[g] += c[0]*w[0] + c[1]*w[1] + c[2]*w[2] + c[3]*w[3];
      }
    }
    float bh = bhead[t];
    #pragma unroll
    for (int g = 0; g < 4; ++g) {
      float r = fmaxf(a2[g] + bh, 0.f);
      #pragma unroll
      for (int rr = 0; rr < 8; ++rr)
        out[(size_t)(rowbase + g*8 + rr)*HIDN + t] = r;
    }
  }
}

extern "C" void kernel_launch(void* const* d_in, const int* in_sizes, int n_in,
                              void* d_out, int out_size, void* d_ws, size_t ws_size,
                              hipStream_t stream) {
    const float* hs    = (const float*)d_in[0];
    const float* eps   = (const float*)d_in[1];
    const float* WQ    = (const float*)d_in[2];
    const float* bQ    = (const float*)d_in[3];
    const float* WK    = (const float*)d_in[4];
    const float* bK    = (const float*)d_in[5];
    const float* Wmu   = (const float*)d_in[6];
    const float* bmu   = (const float*)d_in[7];
    const float* Wvar  = (const float*)d_in[8];
    const float* bvar  = (const float*)d_in[9];
    const float* vocab = (const float*)d_in[10];
    const float* Wsum  = (const float*)d_in[11];
    const float* bsum  = (const float*)d_in[12];
    const float* Whead = (const float*)d_in[13];
    const float* bhead = (const float*)d_in[14];
    float* o = (float*)d_out;
    int Btot = in_sizes[0] / HIDN;
    dim3 grid(Btot / ROWSB), block(256);
    hipLaunchKernelGGL(mac_fused, grid, block, 0, stream,
                       hs, eps, WQ, bQ, WK, bK, Wmu, bmu, Wvar, bvar,
                       vocab, Wsum, bsum, Whead, bhead, o, Btot);
}

// Round 2
// 475.507 us; speedup vs baseline: 1.0312x; 1.0312x over previous
//
#include <hip/hip_runtime.h>

#define ROWSB 32
#define HIDN 256
#define TT 8
#define EPSI 1e-6f
#define HAS 260      // ha row stride (floats): (65*r + q) % 8 spreads bank groups
#define SVS 260      // sorted-vocab row stride (257 used + 3 INF pad)
#define TBSTR 40
#define NCELL 128
#define WS_LUT_F   (32*SVS)           // float-index of LUT (32*128 ushort = 2048 floats)
#define WS_DINFO_F (32*SVS + 2048)    // float-index of per-dim (base,scale) float2

__device__ __forceinline__ void ld4(float* d, const float* p) {
  float4 v = *(const float4*)p;
  d[0] = v.x; d[1] = v.y; d[2] = v.z; d[3] = v.w;
}

// ---------- pre-pass: per-dim bitonic sort of vocab + lower-bound LUT ----------
__global__ __launch_bounds__(256)
void sort_vocab(const float* __restrict__ vocab, float* __restrict__ ws) {
  __shared__ float arr[512];
  const int d = blockIdx.x;
  const int t = threadIdx.x;
  arr[t] = (t < 257) ? vocab[t*32 + d] : 3.0e38f;
  arr[t+256] = (t == 0) ? vocab[256*32 + d] : 3.0e38f;  // t+256==256 only for t==0
  __syncthreads();
  for (int k = 2; k <= 512; k <<= 1) {
    for (int j = k >> 1; j > 0; j >>= 1) {
      #pragma unroll
      for (int h = 0; h < 2; ++h) {
        int i = t + h*256;
        int ixj = i ^ j;
        if (ixj > i) {
          float a = arr[i], b = arr[ixj];
          bool up = ((i & k) == 0);
          if ((a > b) == up) { arr[i] = b; arr[ixj] = a; }
        }
      }
      __syncthreads();
    }
  }
  // write sorted values (+INF pad to SVS)
  #pragma unroll
  for (int h = 0; h < 2; ++h) {
    int i = t + h*256;
    if (i < SVS) ws[d*SVS + i] = (i < 257) ? arr[i] : 3.0e38f;
  }
  float base = arr[0];
  float maxv = arr[256];
  float scale = (float)NCELL / fmaxf(maxv - base, 1e-30f);
  if (t == 0) {
    float2* dinfo = (float2*)(ws + WS_DINFO_F);
    dinfo[d] = make_float2(base, scale);
  }
  if (t < NCELL) {
    float target = base + (float)t * (maxv - base) * (1.0f/(float)NCELL);
    int lo = 0, hi = 257;
    while (lo < hi) { int mid = (lo+hi)>>1; if (arr[mid] < target) lo = mid+1; else hi = mid; }
    ((unsigned short*)(ws + WS_LUT_F))[d*NCELL + t] = (unsigned short)lo;
  }
}

// ---------- main fused kernel: everything wave-private except vocab staging ----------
__global__ __launch_bounds__(256, 2)
void mac_fused(const float* __restrict__ hs, const float* __restrict__ eps,
               const float* __restrict__ WQ, const float* __restrict__ bQ,
               const float* __restrict__ WK, const float* __restrict__ bK,
               const float* __restrict__ Wmu, const float* __restrict__ bmu,
               const float* __restrict__ Wvar, const float* __restrict__ bvar,
               const float* __restrict__ vocab,
               const float* __restrict__ Wsum, const float* __restrict__ bsum,
               const float* __restrict__ Whead, const float* __restrict__ bhead,
               const float* __restrict__ ws, float* __restrict__ out, int Btot)
{
  // 80384 B total -> 2 blocks/CU
  __shared__ __align__(16) float ha[ROWSB*HAS];            // wave-private rows; aliases hs staging
  __shared__ __align__(16) float sV[32*SVS];               // sorted vocab [dim][257+pad]
  __shared__ __align__(16) unsigned short lut[32*NCELL];   // lower-bound LUT
  __shared__ __align__(16) float tokbuf[ROWSB*TBSTR];      // wave-private; tail reused as comm buf
  __shared__ float dbase[32], dscale[32];
  __shared__ float ivbuf[ROWSB], finbuf[ROWSB];

  const int t   = threadIdx.x;
  const int c4  = t & 63;
  const int w   = t >> 6;         // wave id == row-group == agent group
  const int sr  = t >> 3;         // sampling row (0..31)
  const int sc8 = t & 7;          // sampling dim-quad (dims 4*sc8..+3)
  const int d0u = (c4 << 2) & 31; // unified-layout comp dims
  const int tg  = c4 >> 3;        // token slot of this thread's cols
  const int rowbase = blockIdx.x * ROWSB;

  float Qr[8][4], Vr[8][4], Kr[8][4], MSGr[8][4];
  float eosv[4];
  unsigned fin = 0u;

  // ---------------- staging ----------------
  {
    const float* hp = hs + (size_t)(rowbase + w*8)*HIDN + c4*4;
    #pragma unroll
    for (int rr = 0; rr < 8; ++rr)
      *(float4*)&ha[(w*8+rr)*HAS + c4*4] = *(const float4*)(hp + (size_t)rr*HIDN);
  }
  for (int i = t; i < 32*SVS/4; i += 256)                 // 2080 float4
    *(float4*)&sV[i*4] = *(const float4*)(ws + (size_t)i*4);
  for (int i = t; i < 512; i += 256)                      // LUT: 2048 floats
    ((float4*)lut)[i] = ((const float4*)(ws + WS_LUT_F))[i];
  if (t < 32) {
    float2 bs_ = ((const float2*)(ws + WS_DINFO_F))[t];
    dbase[t] = bs_.x; dscale[t] = bs_.y;
  }
  if (t < ROWSB) finbuf[t] = 0.f;
  ld4(eosv, vocab + 256*32 + d0u);
  {
    float bq[4], bk[4];
    ld4(bq, bQ + c4*4); ld4(bk, bK + c4*4);
    #pragma unroll
    for (int rr = 0; rr < 8; ++rr) {
      #pragma unroll
      for (int k = 0; k < 4; ++k) { Qr[rr][k] = bq[k]; Vr[rr][k] = bk[k]; }
    }
  }
  __threadfence_block();   // own-wave ha(hs) writes visible to cross-lane reads

  // ------------- initial GEMM: Q = hs@WQ + bQ ; V = hs@WK + bK -------------
  #pragma unroll 2
  for (int jq = 0; jq < 64; ++jq) {
    float hsq[8][4];
    #pragma unroll
    for (int rr = 0; rr < 8; ++rr) ld4(hsq[rr], &ha[(w*8+rr)*HAS + jq*4]);  // wave broadcast
    #pragma unroll
    for (int m = 0; m < 4; ++m) {
      float wq[4], wk[4];
      ld4(wq, WQ + (size_t)(jq*4+m)*HIDN + c4*4);
      ld4(wk, WK + (size_t)(jq*4+m)*HIDN + c4*4);
      #pragma unroll
      for (int rr = 0; rr < 8; ++rr) {
        #pragma unroll
        for (int k = 0; k < 4; ++k) {
          Qr[rr][k] += hsq[rr][m]*wq[k];
          Vr[rr][k] += hsq[rr][m]*wk[k];
        }
      }
    }
  }
  {
    float bk[4]; ld4(bk, bK + c4*4);
    #pragma unroll
    for (int rr = 0; rr < 8; ++rr) {
      #pragma unroll
      for (int k = 0; k < 4; ++k) {
        Qr[rr][k] *= (1.0f/256.0f);   // bake NF^2: logit = -(Qr*Kr)
        Kr[rr][k]   = bk[k];
        MSGr[rr][k] = 0.f;
      }
    }
  }
  float bm[4], bv[4], dbr[4], dsr[4];
  ld4(bm, bmu + sc8*4); ld4(bv, bvar + sc8*4);

  __syncthreads();        // the ONLY block-wide barrier: sV/lut/dinfo/finbuf ready
  #pragma unroll
  for (int k = 0; k < 4; ++k) { dbr[k] = dbase[sc8*4+k]; dsr[k] = dscale[sc8*4+k]; }

  // ---------------- token recurrence (all wave-private) ----------------
  for (int it = 0; it < TT; ++it) {
    // --- incremental K: K += token_{it-1} @ WK[rows 32(it-1)..32it) ---
    if (it > 0) {
      const float* Wr = WK + (size_t)((it-1)*32)*HIDN + c4*4;
      #pragma unroll 2
      for (int cq = 0; cq < 8; ++cq) {
        float tq[8][4];
        #pragma unroll
        for (int rr = 0; rr < 8; ++rr) ld4(tq[rr], &tokbuf[(w*8+rr)*TBSTR + cq*4]); // broadcast
        #pragma unroll
        for (int m = 0; m < 4; ++m) {
          float wv[4]; ld4(wv, Wr + (size_t)(cq*4+m)*HIDN);
          #pragma unroll
          for (int rr = 0; rr < 8; ++rr) {
            #pragma unroll
            for (int k = 0; k < 4; ++k) Kr[rr][k] += tq[rr][m]*wv[k];
          }
        }
      }
    }

    // --- softmax(-(Q*K)) without max-sub (|logit|<1e-3); store e*V, 1/s via ivbuf ---
    #pragma unroll
    for (int rr = 0; rr < 8; ++rr) {
      float e[4]; float s = 0.f;
      #pragma unroll
      for (int k = 0; k < 4; ++k) { e[k] = __expf(-(Qr[rr][k]*Kr[rr][k])); s += e[k]; }
      #pragma unroll
      for (int off = 32; off >= 1; off >>= 1) s += __shfl_xor(s, off);
      if (c4 == rr) ivbuf[w*8+rr] = 1.0f / s;
      *(float4*)&ha[(w*8+rr)*HAS + c4*4] =
          make_float4(e[0]*Vr[rr][0], e[1]*Vr[rr][1], e[2]*Vr[rr][2], e[3]*Vr[rr][3]);
    }
    __threadfence_block();

    // --- fused GEMV + sample + quantize: thread = (row sr, dims 4*sc8..+3) ---
    {
      float muv[4] = {0,0,0,0}, lvv[4] = {0,0,0,0};
      const float* wmp = Wmu + sc8*4;
      const float* wvp = Wvar + sc8*4;
      const float* harow = &ha[sr*HAS];
      #pragma unroll 2
      for (int jq = 0; jq < 64; ++jq) {
        float h[4]; ld4(h, harow + jq*4);   // 8-lane broadcast, rows conflict-free
        #pragma unroll
        for (int m = 0; m < 4; ++m) {
          float wm[4], wv2[4];
          ld4(wm,  wmp + (size_t)(jq*4+m)*32);
          ld4(wv2, wvp + (size_t)(jq*4+m)*32);
          #pragma unroll
          for (int k = 0; k < 4; ++k) { muv[k] += h[m]*wm[k]; lvv[k] += h[m]*wv2[k]; }
        }
      }
      float ivr = ivbuf[sr];
      float msk = 1.0f - finbuf[sr];
      float ep[4]; ld4(ep, eps + ((size_t)it*Btot + rowbase + sr)*32 + sc8*4);
      float md[4];
      #pragma unroll
      for (int k = 0; k < 4; ++k) {
        float mu = muv[k]*ivr + bm[k];
        float lv = lvv[k]*ivr + bv[k];
        float x  = ep[k]*__expf(0.5f*lv) + mu;
        int c = (int)((x - dbr[k]) * dsr[k]);
        c = min(max(c, 0), NCELL-1);
        int idx = (int)lut[(sc8*4+k)*NCELL + c];
        const float* sp = &sV[(sc8*4+k)*SVS];
        float v = sp[idx];
        while (v < x) { ++idx; v = sp[idx]; }   // pads are +INF -> terminates
        float dn = v - x;
        float dp = (idx > 0) ? (x - sp[idx-1]) : 3.0e38f;
        md[k] = fminf(dn, dp);
      }
      *(float4*)&tokbuf[sr*TBSTR + sc8*4] =
          make_float4(md[0]*md[0]*msk, md[1]*md[1]*msk, md[2]*md[2]*msk, md[3]*md[3]*msk);
    }
    __threadfence_block();

    // --- hit detection + message update (unified layout, wave-private) ---
    {
      float tokr[8][4];
      #pragma unroll
      for (int rr = 0; rr < 8; ++rr) ld4(tokr[rr], &tokbuf[(w*8+rr)*TBSTR + d0u]);
      unsigned newfin = fin;
      #pragma unroll
      for (int rr = 0; rr < 8; ++rr) {
        float pd = 0.f, ed = 0.f;
        #pragma unroll
        for (int k = 0; k < 4; ++k) { float dm = tokr[rr][k]-MSGr[rr][k]; pd += dm*dm; }
        if (tg == 0) {
          #pragma unroll
          for (int k = 0; k < 4; ++k) { float de = tokr[rr][k]-eosv[k]; ed += de*de; }
        }
        pd += __shfl_xor(pd, 1); ed += __shfl_xor(ed, 1);
        pd += __shfl_xor(pd, 2); ed += __shfl_xor(ed, 2);
        pd += __shfl_xor(pd, 4); ed += __shfl_xor(ed, 4);
        bool lane_hit = (tg < it && pd < EPSI) || (tg == 0 && ed < EPSI);
        bool hit = (__ballot(lane_hit) != 0ull);
        if (hit) {
          if ((tg == it) && !((fin >> rr) & 1u)) {
            #pragma unroll
            for (int k = 0; k < 4; ++k) tokr[rr][k] = eosv[k];
          }
          newfin |= (1u << rr);
        }
        if (tg == it) {
          #pragma unroll
          for (int k = 0; k < 4; ++k) MSGr[rr][k] = tokr[rr][k];
        }
      }
      if (tg == it) {
        #pragma unroll
        for (int rr = 0; rr < 8; ++rr)
          *(float4*)&tokbuf[(w*8+rr)*TBSTR + d0u] =
              make_float4(MSGr[rr][0], MSGr[rr][1], MSGr[rr][2], MSGr[rr][3]);
      }
      if (c4 == 0) {
        #pragma unroll
        for (int rr = 0; rr < 8; ++rr)
          finbuf[w*8+rr] = ((newfin >> rr) & 1u) ? 1.f : 0.f;
      }
      fin = newfin;
    }
    __threadfence_block();
  }

  // ---------------- final: comm sum + two GEMVs + relu (wave-private) ----------------
  float* commw = &tokbuf[w*8*TBSTR];   // 320 floats >= 260, own wave's tokbuf region
  {
    float cs[4] = {0,0,0,0};
    #pragma unroll
    for (int rr = 0; rr < 8; ++rr) {
      #pragma unroll
      for (int k = 0; k < 4; ++k) cs[k] += MSGr[rr][k];
    }
    const float i7 = 1.0f/7.0f;
    *(float4*)&commw[c4*4] = make_float4(cs[0]*i7, cs[1]*i7, cs[2]*i7, cs[3]*i7);
  }
  __threadfence_block();
  {
    float a1[4]; ld4(a1, bsum + c4*4);
    #pragma unroll 2
    for (int jq = 0; jq < 64; ++jq) {
      float cv[4]; ld4(cv, commw + jq*4);       // wave broadcast
      #pragma unroll
      for (int m = 0; m < 4; ++m) {
        float w4[4]; ld4(w4, Wsum + (size_t)(jq*4+m)*HIDN + c4*4);
        #pragma unroll
        for (int k = 0; k < 4; ++k) a1[k] += cv[m]*w4[k];
      }
    }
    *(float4*)&commw[c4*4] = make_float4(a1[0], a1[1], a1[2], a1[3]);  // lockstep-safe overwrite
  }
  __threadfence_block();
  {
    float a2[4]; ld4(a2, bhead + c4*4);
    #pragma unroll 2
    for (int jq = 0; jq < 64; ++jq) {
      float cv[4]; ld4(cv, commw + jq*4);
      #pragma unroll
      for (int m = 0; m < 4; ++m) {
        float w4[4]; ld4(w4, Whead + (size_t)(jq*4+m)*HIDN + c4*4);
        #pragma unroll
        for (int k = 0; k < 4; ++k) a2[k] += cv[m]*w4[k];
      }
    }
    float4 r = make_float4(fmaxf(a2[0],0.f), fmaxf(a2[1],0.f), fmaxf(a2[2],0.f), fmaxf(a2[3],0.f));
    #pragma unroll
    for (int rr = 0; rr < 8; ++rr)
      *(float4*)&out[(size_t)(rowbase + w*8 + rr)*HIDN + c4*4] = r;
  }
}

extern "C" void kernel_launch(void* const* d_in, const int* in_sizes, int n_in,
                              void* d_out, int out_size, void* d_ws, size_t ws_size,
                              hipStream_t stream) {
    const float* hs    = (const float*)d_in[0];
    const float* eps   = (const float*)d_in[1];
    const float* WQ    = (const float*)d_in[2];
    const float* bQ    = (const float*)d_in[3];
    const float* WK    = (const float*)d_in[4];
    const float* bK    = (const float*)d_in[5];
    const float* Wmu   = (const float*)d_in[6];
    const float* bmu   = (const float*)d_in[7];
    const float* Wvar  = (const float*)d_in[8];
    const float* bvar  = (const float*)d_in[9];
    const float* vocab = (const float*)d_in[10];
    const float* Wsum  = (const float*)d_in[11];
    const float* bsum  = (const float*)d_in[12];
    const float* Whead = (const float*)d_in[13];
    const float* bhead = (const float*)d_in[14];
    float* o = (float*)d_out;
    float* wsf = (float*)d_ws;
    int Btot = in_sizes[0] / HIDN;
    hipLaunchKernelGGL(sort_vocab, dim3(32), dim3(256), 0, stream, vocab, wsf);
    hipLaunchKernelGGL(mac_fused, dim3(Btot / ROWSB), dim3(256), 0, stream,
                       hs, eps, WQ, bQ, WK, bK, Wmu, bmu, Wvar, bvar,
                       vocab, Wsum, bsum, Whead, bhead, wsf, o, Btot);
}